// Round 9
// baseline (157.251 us; speedup 1.0000x reference)
//
#include <hip/hip_runtime.h>
#include <math.h>

#define G_GAMES 8
#define D_IN 512
#define H1 1024
#define H2 1024
#define A_DIM 128
#define B_ROWS 8192

typedef short bf16x8 __attribute__((ext_vector_type(8)));
typedef float f32x4 __attribute__((ext_vector_type(4)));

// ---------- workspace layout (bytes) ----------
#define WS_OFF   0u
#define WS_PERM  256u
#define WS_SPERM 33280u
#define WS_W1T   (WS_SPERM + B_ROWS*D_IN*2u)          // G*H1*D_IN bf16
#define WS_W2T   (WS_W1T + G_GAMES*D_IN*H1*2u)        // H2*H1 bf16
#define WS_W3T   (WS_W2T + (unsigned)H1*H2*2u)        // G*A*H2 bf16
#define WS_H1    (WS_W3T + G_GAMES*H2*A_DIM*2u)       // B*H1 bf16
#define WS_HF    WS_SPERM

__device__ __forceinline__ unsigned short f2bf(float x) {
  union { float f; unsigned int u; } v; v.f = x;
  unsigned int r = v.u + 0x7fffu + ((v.u >> 16) & 1u);
  return (unsigned short)(r >> 16);
}

__device__ __forceinline__ unsigned int cvt_pk_bf16(float lo, float hi) {
  unsigned int r;
  asm("v_cvt_pk_bf16_f32 %0, %1, %2" : "=v"(r) : "v"(lo), "v"(hi));
  return r;
}

__device__ __forceinline__ void async_load16(const void* gptr, void* ldsptr) {
  __builtin_amdgcn_global_load_lds(
      (const __attribute__((address_space(1))) unsigned int*)gptr,
      (__attribute__((address_space(3))) unsigned int*)ldsptr,
      16, 0, 0);
}

// ---------------- stable counting sort (256 threads, 32 elems each) ----------------
// ALL per-thread arrays statically indexed (rule #20).
__device__ void sort_256(const int* __restrict__ idx, int* __restrict__ perm,
                         int* __restrict__ off) {
  __shared__ int wtot[4][9];
  __shared__ int wbase[4][9];
  __shared__ int offs[9];
  const int t = threadIdx.x, lane = t & 63, wave = t >> 6;
  int my[32];
#pragma unroll
  for (int i = 0; i < 8; ++i) {
    const int4 a = *(const int4*)(idx + t * 32 + i * 4);
    my[i*4+0] = a.x; my[i*4+1] = a.y; my[i*4+2] = a.z; my[i*4+3] = a.w;
  }
  int local[8];
#pragma unroll
  for (int g = 0; g < 8; ++g) {
    int c = 0;
#pragma unroll
    for (int i = 0; i < 32; ++i) c += (my[i] == g) ? 1 : 0;
    local[g] = c;
  }
  int incl[8];
#pragma unroll
  for (int g = 0; g < 8; ++g) {
    int v = local[g];
#pragma unroll
    for (int d = 1; d < 64; d <<= 1) {
      const int n = __shfl_up(v, d);
      if (lane >= d) v += n;
    }
    incl[g] = v;
  }
  if (lane == 63) {
#pragma unroll
    for (int g = 0; g < 8; ++g) wtot[wave][g] = incl[g];
  }
  __syncthreads();
  if (t < 8) {
    int s = 0;
#pragma unroll
    for (int w = 0; w < 4; ++w) { wbase[w][t] = s; s += wtot[w][t]; }
    wtot[0][t] = s;
  }
  __syncthreads();
  if (t == 0) {
    int s = 0;
#pragma unroll
    for (int g = 0; g < 8; ++g) { offs[g] = s; off[g] = s; s += wtot[0][g]; }
    offs[8] = s; off[8] = s;
  }
  __syncthreads();
#pragma unroll
  for (int g = 0; g < 8; ++g) {
    int sg = offs[g] + wbase[wave][g] + (incl[g] - local[g]);
#pragma unroll
    for (int i = 0; i < 32; ++i) {
      const bool m = (my[i] == g);
      if (m) perm[sg] = t * 32 + i;
      sg += m ? 1 : 0;
    }
  }
}

// ------------- fp32 [R][C] -> bf16 [C][R] transpose tile (64x64), LDS slice 8704B ----
__device__ void trans_tile_ws(char* ldsbuf, const float* __restrict__ in,
                              unsigned short* __restrict__ out,
                              int R, int C, int xt, int yt, int z) {
  in  += (size_t)z * R * C;
  out += (size_t)z * R * C;
  unsigned short (*tl)[68] = (unsigned short(*)[68])ldsbuf;
  const int c0 = xt * 64, r0 = yt * 64;
  const int t = threadIdx.x;
#pragma unroll
  for (int pass = 0; pass < 4; ++pass) {
    const int id = pass * 256 + t;
    const int r = id >> 4, f4c = (id & 15) << 2;
    const float4 v = *(const float4*)(in + (size_t)(r0 + r) * C + c0 + f4c);
    uint2 w;
    w.x = cvt_pk_bf16(v.x, v.y);
    w.y = cvt_pk_bf16(v.z, v.w);
    *(uint2*)&tl[r][f4c] = w;
  }
  __syncthreads();
#pragma unroll
  for (int pass = 0; pass < 2; ++pass) {
    const int cc = t >> 2, k0 = ((t & 3) << 3) + (pass << 5);
    unsigned short u[8];
#pragma unroll
    for (int j = 0; j < 8; ++j) u[j] = tl[k0 + j][cc];
    uint4 v;
    v.x = (unsigned)u[0] | ((unsigned)u[1] << 16);
    v.y = (unsigned)u[2] | ((unsigned)u[3] << 16);
    v.z = (unsigned)u[4] | ((unsigned)u[5] << 16);
    v.w = (unsigned)u[6] | ((unsigned)u[7] << 16);
    *(uint4*)(out + (size_t)(c0 + cc) * R + r0 + k0) = v;
  }
}

__device__ __forceinline__ bool seg_map(const int* __restrict__ off, int T,
                                        int& g, int& seg1, int& row0) {
  int base = 0;
  for (int gg = 0; gg < 8; ++gg) {
    const int s = off[gg], e = off[gg + 1];
    const int nt = (e - s + 127) >> 7;
    if (T < base + nt) { g = gg; seg1 = e; row0 = s + (T - base) * 128; return true; }
    base += nt;
  }
  return false;
}

__device__ __forceinline__ bool seg_map16(const int* __restrict__ off, int T,
                                          int& g, int& seg1, int& row0) {
  int base = 0;
  for (int gg = 0; gg < 8; ++gg) {
    const int s = off[gg], e = off[gg + 1];
    const int nt = (e - s + 15) >> 4;
    if (T < base + nt) { g = gg; seg1 = e; row0 = s + (T - base) * 16; return true; }
    base += nt;
  }
  return false;
}

// Epilogue: stage bf16 C-tile in LDS (row stride 264 B), then 16B/lane row stores.
__device__ __forceinline__ void epilogue_bf16(char* smem, const f32x4 acc[4][4],
                                              const float* bj, int tid,
                                              unsigned short* __restrict__ outp,
                                              size_t ldOut, int row0, int col0,
                                              int vrows) {
  const int lane = tid & 63, wave = tid >> 6;
  const int wm = wave & 1, wn = wave >> 1;
  const int sw = lane & 15, quad = lane >> 4;
  __syncthreads();
#pragma unroll
  for (int i = 0; i < 4; ++i)
#pragma unroll
    for (int j = 0; j < 4; ++j)
#pragma unroll
      for (int r = 0; r < 4; ++r) {
        const int row = wm * 64 + i * 16 + quad * 4 + r;
        const int col = wn * 64 + j * 16 + sw;
        const float v = fmaxf(acc[i][j][r] + bj[j], 0.0f);
        *(unsigned short*)(smem + row * 264 + col * 2) = f2bf(v);
      }
  __syncthreads();
#pragma unroll
  for (int q = 0; q < 8; ++q) {
    const int idxq = q * 256 + tid;
    const int row = idxq >> 4, ch = idxq & 15;
    if (row < vrows) {
      const uint2 lo = *(const uint2*)(smem + row * 264 + ch * 16);
      const uint2 hi = *(const uint2*)(smem + row * 264 + ch * 16 + 8);
      uint4 v; v.x = lo.x; v.y = lo.y; v.z = hi.x; v.w = hi.y;
      *(uint4*)((char*)outp + ((size_t)(row0 + row) * ldOut + col0 + ch * 8) * 2) = v;
    }
  }
}

// ------------- GEMM1 tile (fused gather), dbuf, 128x128 (best-measured) ----
__device__ void gemm1_tile(const float* __restrict__ state,
                           const int* __restrict__ perm,
                           const unsigned short* __restrict__ W1T,
                           const float* __restrict__ b1,
                           const int* __restrict__ off,
                           unsigned short* __restrict__ h1out,
                           int T, char* smem, int tid) {
  int g, seg1, row0;
  if (!seg_map(off, T % 72, g, seg1, row0)) return;
  const int col0 = (T / 72) * 128;
  const int lane = tid & 63, wave = tid >> 6;
  const int wm = wave & 1, wn = wave >> 1;
  const int sw = lane & 15, quad = lane >> 4;
  const int lc = lane & 7;
  const int gcol = ((lane & 7) ^ (lane >> 3)) << 3;
  const float* aS[4];
  int ldsA[4];
  const unsigned short* bP[4];
#pragma unroll
  for (int c = 0; c < 4; ++c) {
    const int rl = wave * 32 + c * 8 + (lane >> 3);
    int p = row0 + rl;
    if (p > seg1 - 1) p = seg1 - 1;
    aS[c]  = state + (size_t)perm[p] * D_IN + lc * 8;
    ldsA[c] = rl * 128 + ((lc ^ (rl & 7)) << 4);
    bP[c]  = W1T + (size_t)g * H1 * D_IN + (size_t)(col0 + rl) * D_IN + gcol;
  }
  char* A0 = smem;          char* A1 = smem + 16384;
  char* B0 = smem + 32768;  char* B1 = smem + 49152;
  const int mA = wm * 64 + sw, nB = wn * 64 + sw;
  f32x4 acc[4][4] = {};
  {
    float4 t0[4], t1[4];
#pragma unroll
    for (int c = 0; c < 4; ++c) {
      t0[c] = *(const float4*)(aS[c]);
      t1[c] = *(const float4*)(aS[c] + 4);
      async_load16(bP[c], B0 + (wave * 32 + c * 8) * 128);
    }
#pragma unroll
    for (int c = 0; c < 4; ++c) {
      uint4 pk;
      pk.x = cvt_pk_bf16(t0[c].x, t0[c].y);
      pk.y = cvt_pk_bf16(t0[c].z, t0[c].w);
      pk.z = cvt_pk_bf16(t1[c].x, t1[c].y);
      pk.w = cvt_pk_bf16(t1[c].z, t1[c].w);
      *(uint4*)(A0 + ldsA[c]) = pk;
    }
  }
  const int NIT = D_IN >> 6;
#pragma unroll 2
  for (int k = 0; k < NIT; ++k) {
    __syncthreads();
    char* A = (k & 1) ? A1 : A0;
    char* B = (k & 1) ? B1 : B0;
    float4 t0[4], t1[4];
    const bool pf = (k + 1 < NIT);
    if (pf) {
      char* Bn = (k & 1) ? B0 : B1;
      const int koff = (k + 1) << 6;
#pragma unroll
      for (int c = 0; c < 4; ++c) {
        t0[c] = *(const float4*)(aS[c] + koff);
        t1[c] = *(const float4*)(aS[c] + koff + 4);
        async_load16(bP[c] + koff, Bn + (wave * 32 + c * 8) * 128);
      }
    }
#pragma unroll
    for (int ks = 0; ks < 2; ++ks) {
      const int u = ((((ks << 2) + quad) ^ (sw & 7)) << 4);
      bf16x8 aF[4], bF[4];
#pragma unroll
      for (int i = 0; i < 4; ++i) {
        aF[i] = *(const bf16x8*)(A + (mA + i * 16) * 128 + u);
        bF[i] = *(const bf16x8*)(B + (nB + i * 16) * 128 + u);
      }
#pragma unroll
      for (int i = 0; i < 4; ++i)
#pragma unroll
        for (int j = 0; j < 4; ++j)
          acc[i][j] = __builtin_amdgcn_mfma_f32_16x16x32_bf16(aF[i], bF[j], acc[i][j], 0, 0, 0);
    }
    if (pf) {
      char* An = (k & 1) ? A0 : A1;
#pragma unroll
      for (int c = 0; c < 4; ++c) {
        uint4 pk;
        pk.x = cvt_pk_bf16(t0[c].x, t0[c].y);
        pk.y = cvt_pk_bf16(t0[c].z, t0[c].w);
        pk.z = cvt_pk_bf16(t1[c].x, t1[c].y);
        pk.w = cvt_pk_bf16(t1[c].z, t1[c].w);
        *(uint4*)(An + ldsA[c]) = pk;
      }
    }
  }
  const float* bg = b1 + g * H1;
  float bj[4];
#pragma unroll
  for (int j = 0; j < 4; ++j) bj[j] = bg[col0 + wn * 64 + j * 16 + sw];
  const int vrows = min(128, seg1 - row0);
  epilogue_bf16(smem, acc, bj, tid, h1out, H1, row0, col0, vrows);
}

// ------------- GEMM2 tile, dbuf 128x128 (R7 best-measured form) -------------
__device__ void gemm2_tile(const unsigned short* __restrict__ h1in,
                           const unsigned short* __restrict__ W2T,
                           const float* __restrict__ b2,
                           unsigned short* __restrict__ hfout,
                           int T, char* smem, int tid) {
  const int row0 = (T & 63) * 128, col0 = (T >> 6) * 128;
  const int lane = tid & 63, wave = tid >> 6;
  const int wm = wave & 1, wn = wave >> 1;
  const int sw = lane & 15, quad = lane >> 4;
  const int gcol = ((lane & 7) ^ (lane >> 3)) << 3;
  const unsigned short* aP[4];
  const unsigned short* bP[4];
#pragma unroll
  for (int c = 0; c < 4; ++c) {
    const int rl = wave * 32 + c * 8 + (lane >> 3);
    aP[c] = h1in + (size_t)(row0 + rl) * H1 + gcol;
    bP[c] = W2T + (size_t)(col0 + rl) * H1 + gcol;
  }
  char* A0 = smem;          char* A1 = smem + 16384;
  char* B0 = smem + 32768;  char* B1 = smem + 49152;
  const int mA = wm * 64 + sw, nB = wn * 64 + sw;
  f32x4 acc[4][4] = {};
#pragma unroll
  for (int c = 0; c < 4; ++c) {
    async_load16(aP[c], A0 + (wave * 32 + c * 8) * 128);
    async_load16(bP[c], B0 + (wave * 32 + c * 8) * 128);
  }
  const int NIT = H1 >> 6;
#pragma unroll 2
  for (int k = 0; k < NIT; ++k) {
    __syncthreads();
    char* A = (k & 1) ? A1 : A0;
    char* B = (k & 1) ? B1 : B0;
    if (k + 1 < NIT) {
      char* An = (k & 1) ? A0 : A1;
      char* Bn = (k & 1) ? B0 : B1;
      const int koff = (k + 1) << 6;
#pragma unroll
      for (int c = 0; c < 4; ++c) {
        async_load16(aP[c] + koff, An + (wave * 32 + c * 8) * 128);
        async_load16(bP[c] + koff, Bn + (wave * 32 + c * 8) * 128);
      }
    }
#pragma unroll
    for (int ks = 0; ks < 2; ++ks) {
      const int u = ((((ks << 2) + quad) ^ (sw & 7)) << 4);
      bf16x8 aF[4], bF[4];
#pragma unroll
      for (int i = 0; i < 4; ++i) {
        aF[i] = *(const bf16x8*)(A + (mA + i * 16) * 128 + u);
        bF[i] = *(const bf16x8*)(B + (nB + i * 16) * 128 + u);
      }
#pragma unroll
      for (int i = 0; i < 4; ++i)
#pragma unroll
        for (int j = 0; j < 4; ++j)
          acc[i][j] = __builtin_amdgcn_mfma_f32_16x16x32_bf16(aF[i], bF[j], acc[i][j], 0, 0, 0);
    }
  }
  float bj[4];
#pragma unroll
  for (int j = 0; j < 4; ++j) bj[j] = b2[col0 + wn * 64 + j * 16 + sw];
  epilogue_bf16(smem, acc, bj, tid, hfout, H2, row0, col0, 128);
}

// ------------- GEMM3 tile: 16x128, dbuf BK=64 — ~520 blocks = 2/CU -------------
// 4 waves: wave w owns rows 0..15 x cols [w*32, w*32+32). A-stage: waves 0,1 only
// (one async_load16 each, 8 rows). All swizzle formulas row&7-consistent with the
// pre-swizzled global gcol, as in the 32-row version.
__device__ void gemm3_tile(const unsigned short* __restrict__ hf,
                           const unsigned short* __restrict__ W3T,
                           const float* __restrict__ b3,
                           const int* __restrict__ off,
                           const int* __restrict__ perm,
                           float* __restrict__ outp,
                           int T, char* smem, int tid) {
  int g, seg1, row0;
  if (!seg_map16(off, T, g, seg1, row0)) return;
  const int lane = tid & 63, wave = tid >> 6;
  const int sw = lane & 15, quad = lane >> 4;
  const int gcol = ((lane & 7) ^ (lane >> 3)) << 3;
  int q0 = row0 + (wave & 1) * 8 + (lane >> 3);     // valid for waves 0,1
  if (q0 > seg1 - 1) q0 = seg1 - 1;
  const unsigned short* aP = hf + (size_t)perm[q0] * H2 + gcol;
  const unsigned short* bP[4];
#pragma unroll
  for (int c = 0; c < 4; ++c) {
    const int rl = wave * 32 + c * 8 + (lane >> 3);
    bP[c] = W3T + (size_t)g * A_DIM * H2 + (size_t)rl * H2 + gcol;
  }
  char* A0 = smem;         char* A1 = smem + 4096;
  char* B0 = smem + 8192;  char* B1 = smem + 24576;
  const int nB = wave * 32 + sw;
  f32x4 acc[2] = {};
  if (wave < 2) async_load16(aP, A0 + (wave * 8) * 128);
#pragma unroll
  for (int c = 0; c < 4; ++c)
    async_load16(bP[c], B0 + (wave * 32 + c * 8) * 128);
#pragma unroll 2
  for (int k = 0; k < (H2 >> 6); ++k) {
    __syncthreads();
    char* A = (k & 1) ? A1 : A0;
    char* B = (k & 1) ? B1 : B0;
    if (k + 1 < (H2 >> 6)) {
      char* An = (k & 1) ? A0 : A1;
      char* Bn = (k & 1) ? B0 : B1;
      const int koff = (k + 1) << 6;
      if (wave < 2) async_load16(aP + koff, An + (wave * 8) * 128);
#pragma unroll
      for (int c = 0; c < 4; ++c)
        async_load16(bP[c] + koff, Bn + (wave * 32 + c * 8) * 128);
    }
#pragma unroll
    for (int ks = 0; ks < 2; ++ks) {
      const int u = ((((ks << 2) + quad) ^ (sw & 7)) << 4);
      const bf16x8 aF = *(const bf16x8*)(A + sw * 128 + u);
      bf16x8 bF[2];
#pragma unroll
      for (int j = 0; j < 2; ++j)
        bF[j] = *(const bf16x8*)(B + (nB + j * 16) * 128 + u);
#pragma unroll
      for (int j = 0; j < 2; ++j)
        acc[j] = __builtin_amdgcn_mfma_f32_16x16x32_bf16(aF, bF[j], acc[j], 0, 0, 0);
    }
  }
  const float* bg = b3 + g * A_DIM;
  float bj[2];
#pragma unroll
  for (int j = 0; j < 2; ++j) bj[j] = bg[wave * 32 + j * 16 + sw];
  __syncthreads();
#pragma unroll
  for (int j = 0; j < 2; ++j)
#pragma unroll
    for (int r = 0; r < 4; ++r) {
      const int row = quad * 4 + r;                 // 0..15
      const int col = wave * 32 + j * 16 + sw;
      *(float*)(smem + row * 528 + col * 4) = tanhf(acc[j][r] + bj[j]);
    }
  __syncthreads();
#pragma unroll
  for (int qq = 0; qq < 2; ++qq) {
    const int idxq = qq * 256 + tid;                // 512 chunks: 16 rows x 32 of 16B
    const int row = idxq >> 5, ch = idxq & 31;
    if (row0 + row < seg1) {
      const uint4 v = *(const uint4*)(smem + row * 528 + ch * 16);
      *(uint4*)((char*)outp + ((size_t)perm[row0 + row] * A_DIM + ch * 4) * 4) = v;
    }
  }
}

// ================= 4-kernel pipeline =========
// k_pre: sort first (block 0, overlaps transposes) + W1T tiles (gemm1 deps only).
__global__ __launch_bounds__(256) void k_pre(const float* __restrict__ W1,
                                             const int* __restrict__ idx,
                                             unsigned short* __restrict__ W1T,
                                             int* __restrict__ perm,
                                             int* __restrict__ off) {
  __shared__ __align__(16) char tsmem[8704];
  const int b = blockIdx.x;
  if (b == 0) {
    sort_256(idx, perm, off);
  } else {
    const int r0 = b - 1, z = r0 >> 7, r = r0 & 127;
    trans_tile_ws(tsmem, W1, W1T, D_IN, H1, r & 15, r >> 4, z);
  }
}

// k_g1: 576 gemm1 tiles + 512 W2T/W3T rider blocks (needed only by gemm2/gemm3).
__global__ __launch_bounds__(256, 2) void k_g1(const float* __restrict__ state,
                                               const int* __restrict__ perm,
                                               const unsigned short* __restrict__ W1T,
                                               const float* __restrict__ b1,
                                               const int* __restrict__ off,
                                               const float* __restrict__ W2,
                                               const float* __restrict__ W3,
                                               unsigned short* __restrict__ W2T,
                                               unsigned short* __restrict__ W3T,
                                               unsigned short* __restrict__ h1out) {
  __shared__ __align__(16) char smem[65536];
  const int b = blockIdx.x;
  if (b >= 576) {
    const int t = b - 576;
    if (t < 256) {
      trans_tile_ws(smem, W2, W2T, H1, H2, t & 15, t >> 4, 0);
    } else {
      const int r = (t - 256) & 31, z = (t - 256) >> 5;
      trans_tile_ws(smem, W3, W3T, H2, A_DIM, r & 1, r >> 1, z);
    }
    return;
  }
  gemm1_tile(state, perm, W1T, b1, off, h1out, b, smem, threadIdx.x);
}

__global__ __launch_bounds__(256) void k_g2(const unsigned short* __restrict__ h1in,
                                            const unsigned short* __restrict__ W2T,
                                            const float* __restrict__ b2,
                                            unsigned short* __restrict__ hfout) {
  __shared__ __align__(16) char smem[65536];
  gemm2_tile(h1in, W2T, b2, hfout, blockIdx.x, smem, threadIdx.x);
}

__global__ __launch_bounds__(256) void k_g3(const unsigned short* __restrict__ hf,
                                            const unsigned short* __restrict__ W3T,
                                            const float* __restrict__ b3,
                                            const int* __restrict__ off,
                                            const int* __restrict__ perm,
                                            float* __restrict__ outp) {
  __shared__ __align__(16) char smem[40960];
  gemm3_tile(hf, W3T, b3, off, perm, outp, blockIdx.x, smem, threadIdx.x);
}

extern "C" void kernel_launch(void* const* d_in, const int* in_sizes, int n_in,
                              void* d_out, int out_size, void* d_ws, size_t ws_size,
                              hipStream_t stream) {
  (void)in_sizes; (void)n_in; (void)out_size; (void)ws_size;
  const float* state = (const float*)d_in[0];
  const int*   idx   = (const int*)d_in[1];
  const float* W1    = (const float*)d_in[2];
  const float* b1    = (const float*)d_in[3];
  const float* W2    = (const float*)d_in[4];
  const float* b2    = (const float*)d_in[5];
  const float* W3    = (const float*)d_in[6];
  const float* b3    = (const float*)d_in[7];
  float* outp = (float*)d_out;
  char* ws = (char*)d_ws;
  int* off  = (int*)(ws + WS_OFF);
  int* perm = (int*)(ws + WS_PERM);
  unsigned short* W1T   = (unsigned short*)(ws + WS_W1T);
  unsigned short* W2T   = (unsigned short*)(ws + WS_W2T);
  unsigned short* W3T   = (unsigned short*)(ws + WS_W3T);
  unsigned short* h1    = (unsigned short*)(ws + WS_H1);
  unsigned short* hf    = (unsigned short*)(ws + WS_HF);

  hipLaunchKernelGGL(k_pre, dim3(1025), dim3(256), 0, stream,
                     W1, idx, W1T, perm, off);
  hipLaunchKernelGGL(k_g1, dim3(1088), dim3(256), 0, stream,
                     state, perm, W1T, b1, off, W2, W3, W2T, W3T, h1);
  hipLaunchKernelGGL(k_g2, dim3(512), dim3(256), 0, stream, h1, W2T, b2, hf);
  hipLaunchKernelGGL(k_g3, dim3(520), dim3(256), 0, stream, hf, W3T, b3, off, perm, outp);
}

// Round 10
// 152.675 us; speedup vs baseline: 1.0300x; 1.0300x over previous
//
#include <hip/hip_runtime.h>
#include <math.h>

#define G_GAMES 8
#define D_IN 512
#define H1 1024
#define H2 1024
#define A_DIM 128
#define B_ROWS 8192

typedef short bf16x8 __attribute__((ext_vector_type(8)));
typedef float f32x4 __attribute__((ext_vector_type(4)));

// ---------- workspace layout (bytes) ----------
#define WS_OFF   0u
#define WS_PERM  256u
#define WS_SPERM 33280u
#define WS_W1T   (WS_SPERM + B_ROWS*D_IN*2u)          // G*H1*D_IN bf16
#define WS_W2T   (WS_W1T + G_GAMES*D_IN*H1*2u)        // H2*H1 bf16
#define WS_W3T   (WS_W2T + (unsigned)H1*H2*2u)        // G*A*H2 bf16
#define WS_H1    (WS_W3T + G_GAMES*H2*A_DIM*2u)       // B*H1 bf16
#define WS_HF    WS_SPERM
#define WS_CNT   WS_H1    // cnt[32][8] ints: h1 region is dead until k_g1 writes it

__device__ __forceinline__ unsigned short f2bf(float x) {
  union { float f; unsigned int u; } v; v.f = x;
  unsigned int r = v.u + 0x7fffu + ((v.u >> 16) & 1u);
  return (unsigned short)(r >> 16);
}

__device__ __forceinline__ unsigned int cvt_pk_bf16(float lo, float hi) {
  unsigned int r;
  asm("v_cvt_pk_bf16_f32 %0, %1, %2" : "=v"(r) : "v"(lo), "v"(hi));
  return r;
}

__device__ __forceinline__ void async_load16(const void* gptr, void* ldsptr) {
  __builtin_amdgcn_global_load_lds(
      (const __attribute__((address_space(1))) unsigned int*)gptr,
      (__attribute__((address_space(3))) unsigned int*)ldsptr,
      16, 0, 0);
}

// ---------------- parallel stable counting sort ----------------
// Phase A (k_pre, 32 blocks): per-chunk per-game histogram -> cnt[32][8].
__device__ void hist_chunk(const int* __restrict__ idx, int* __restrict__ cnt,
                           int chunk) {
  __shared__ int wc[4][8];
  const int t = threadIdx.x, lane = t & 63, wave = t >> 6;
  const int g = idx[chunk * 256 + t];
#pragma unroll
  for (int g0 = 0; g0 < 8; ++g0) {
    const unsigned long long m = __ballot(g == g0);
    if (lane == 0) wc[wave][g0] = __popcll(m);
  }
  __syncthreads();
  if (t < 8) cnt[chunk * 8 + t] = wc[0][t] + wc[1][t] + wc[2][t] + wc[3][t];
}

// Phase B+C (k_sort, 32 blocks): prefix over cnt + direct scatter.
// dest(e) = gameOff[g] + chunkPrefix[chunk][g] + wavePrefix + rankInWave
// (chunk,wave,lane) order == original order -> stable. One store per thread.
__device__ void scatter_chunk(const int* __restrict__ idx,
                              const int* __restrict__ cnt,
                              int* __restrict__ perm, int* __restrict__ off,
                              int chunk) {
  __shared__ int scnt[256];     // cnt[c][g], c-major
  __shared__ int cbase[8];      // gameOff[g] + chunkPrefix[chunk][g]
  __shared__ int wcn[4][8];     // per-wave per-game counts (this chunk)
  const int t = threadIdx.x, lane = t & 63, wave = t >> 6;
  scnt[t] = cnt[t];
  const int g = idx[chunk * 256 + t];
  __syncthreads();
  if (t < 8) {
    int gt[8];
#pragma unroll
    for (int gg = 0; gg < 8; ++gg) {
      int s = 0;
      for (int c = 0; c < 32; ++c) s += scnt[c * 8 + gg];
      gt[gg] = s;
    }
    int go = 0;
#pragma unroll
    for (int gg = 0; gg < 8; ++gg) if (gg < t) go += gt[gg];
    int cp = 0;
    for (int c = 0; c < chunk; ++c) cp += scnt[c * 8 + t];
    cbase[t] = go + cp;
    if (chunk == 0) {
      off[t] = go;
      if (t == 7) off[8] = go + gt[7];
    }
  }
  // per-wave ballot rank
  const unsigned long long below = (1ull << lane) - 1ull;
  int rank = 0;
#pragma unroll
  for (int g0 = 0; g0 < 8; ++g0) {
    const unsigned long long m = __ballot(g == g0);
    const int r = __popcll(m & below);
    if (g0 == g) rank = r;
    if (lane == 0) wcn[wave][g0] = __popcll(m);
  }
  __syncthreads();
  int wof = 0;
#pragma unroll
  for (int w = 0; w < 4; ++w)
    if (w < wave) wof += wcn[w][g];       // LDS runtime index: fine
  perm[cbase[g] + wof + rank] = chunk * 256 + t;
}

// ------------- fp32 [R][C] -> bf16 [C][R] transpose tile (64x64), LDS slice 8704B ----
__device__ void trans_tile_ws(char* ldsbuf, const float* __restrict__ in,
                              unsigned short* __restrict__ out,
                              int R, int C, int xt, int yt, int z) {
  in  += (size_t)z * R * C;
  out += (size_t)z * R * C;
  unsigned short (*tl)[68] = (unsigned short(*)[68])ldsbuf;
  const int c0 = xt * 64, r0 = yt * 64;
  const int t = threadIdx.x;
#pragma unroll
  for (int pass = 0; pass < 4; ++pass) {
    const int id = pass * 256 + t;
    const int r = id >> 4, f4c = (id & 15) << 2;
    const float4 v = *(const float4*)(in + (size_t)(r0 + r) * C + c0 + f4c);
    uint2 w;
    w.x = cvt_pk_bf16(v.x, v.y);
    w.y = cvt_pk_bf16(v.z, v.w);
    *(uint2*)&tl[r][f4c] = w;
  }
  __syncthreads();
#pragma unroll
  for (int pass = 0; pass < 2; ++pass) {
    const int cc = t >> 2, k0 = ((t & 3) << 3) + (pass << 5);
    unsigned short u[8];
#pragma unroll
    for (int j = 0; j < 8; ++j) u[j] = tl[k0 + j][cc];
    uint4 v;
    v.x = (unsigned)u[0] | ((unsigned)u[1] << 16);
    v.y = (unsigned)u[2] | ((unsigned)u[3] << 16);
    v.z = (unsigned)u[4] | ((unsigned)u[5] << 16);
    v.w = (unsigned)u[6] | ((unsigned)u[7] << 16);
    *(uint4*)(out + (size_t)(c0 + cc) * R + r0 + k0) = v;
  }
}

__device__ __forceinline__ bool seg_map(const int* __restrict__ off, int T,
                                        int& g, int& seg1, int& row0) {
  int base = 0;
  for (int gg = 0; gg < 8; ++gg) {
    const int s = off[gg], e = off[gg + 1];
    const int nt = (e - s + 127) >> 7;
    if (T < base + nt) { g = gg; seg1 = e; row0 = s + (T - base) * 128; return true; }
    base += nt;
  }
  return false;
}

__device__ __forceinline__ bool seg_map16(const int* __restrict__ off, int T,
                                          int& g, int& seg1, int& row0) {
  int base = 0;
  for (int gg = 0; gg < 8; ++gg) {
    const int s = off[gg], e = off[gg + 1];
    const int nt = (e - s + 15) >> 4;
    if (T < base + nt) { g = gg; seg1 = e; row0 = s + (T - base) * 16; return true; }
    base += nt;
  }
  return false;
}

// Epilogue: stage bf16 C-tile in LDS (row stride 264 B), then 16B/lane row stores.
__device__ __forceinline__ void epilogue_bf16(char* smem, const f32x4 acc[4][4],
                                              const float* bj, int tid,
                                              unsigned short* __restrict__ outp,
                                              size_t ldOut, int row0, int col0,
                                              int vrows) {
  const int lane = tid & 63, wave = tid >> 6;
  const int wm = wave & 1, wn = wave >> 1;
  const int sw = lane & 15, quad = lane >> 4;
  __syncthreads();
#pragma unroll
  for (int i = 0; i < 4; ++i)
#pragma unroll
    for (int j = 0; j < 4; ++j)
#pragma unroll
      for (int r = 0; r < 4; ++r) {
        const int row = wm * 64 + i * 16 + quad * 4 + r;
        const int col = wn * 64 + j * 16 + sw;
        const float v = fmaxf(acc[i][j][r] + bj[j], 0.0f);
        *(unsigned short*)(smem + row * 264 + col * 2) = f2bf(v);
      }
  __syncthreads();
#pragma unroll
  for (int q = 0; q < 8; ++q) {
    const int idxq = q * 256 + tid;
    const int row = idxq >> 4, ch = idxq & 15;
    if (row < vrows) {
      const uint2 lo = *(const uint2*)(smem + row * 264 + ch * 16);
      const uint2 hi = *(const uint2*)(smem + row * 264 + ch * 16 + 8);
      uint4 v; v.x = lo.x; v.y = lo.y; v.z = hi.x; v.w = hi.y;
      *(uint4*)((char*)outp + ((size_t)(row0 + row) * ldOut + col0 + ch * 8) * 2) = v;
    }
  }
}

// ------------- GEMM1 tile (fused gather), dbuf, 128x128 (best-measured) ----
__device__ void gemm1_tile(const float* __restrict__ state,
                           const int* __restrict__ perm,
                           const unsigned short* __restrict__ W1T,
                           const float* __restrict__ b1,
                           const int* __restrict__ off,
                           unsigned short* __restrict__ h1out,
                           int T, char* smem, int tid) {
  int g, seg1, row0;
  if (!seg_map(off, T % 72, g, seg1, row0)) return;
  const int col0 = (T / 72) * 128;
  const int lane = tid & 63, wave = tid >> 6;
  const int wm = wave & 1, wn = wave >> 1;
  const int sw = lane & 15, quad = lane >> 4;
  const int lc = lane & 7;
  const int gcol = ((lane & 7) ^ (lane >> 3)) << 3;
  const float* aS[4];
  int ldsA[4];
  const unsigned short* bP[4];
#pragma unroll
  for (int c = 0; c < 4; ++c) {
    const int rl = wave * 32 + c * 8 + (lane >> 3);
    int p = row0 + rl;
    if (p > seg1 - 1) p = seg1 - 1;
    aS[c]  = state + (size_t)perm[p] * D_IN + lc * 8;
    ldsA[c] = rl * 128 + ((lc ^ (rl & 7)) << 4);
    bP[c]  = W1T + (size_t)g * H1 * D_IN + (size_t)(col0 + rl) * D_IN + gcol;
  }
  char* A0 = smem;          char* A1 = smem + 16384;
  char* B0 = smem + 32768;  char* B1 = smem + 49152;
  const int mA = wm * 64 + sw, nB = wn * 64 + sw;
  f32x4 acc[4][4] = {};
  {
    float4 t0[4], t1[4];
#pragma unroll
    for (int c = 0; c < 4; ++c) {
      t0[c] = *(const float4*)(aS[c]);
      t1[c] = *(const float4*)(aS[c] + 4);
      async_load16(bP[c], B0 + (wave * 32 + c * 8) * 128);
    }
#pragma unroll
    for (int c = 0; c < 4; ++c) {
      uint4 pk;
      pk.x = cvt_pk_bf16(t0[c].x, t0[c].y);
      pk.y = cvt_pk_bf16(t0[c].z, t0[c].w);
      pk.z = cvt_pk_bf16(t1[c].x, t1[c].y);
      pk.w = cvt_pk_bf16(t1[c].z, t1[c].w);
      *(uint4*)(A0 + ldsA[c]) = pk;
    }
  }
  const int NIT = D_IN >> 6;
#pragma unroll 2
  for (int k = 0; k < NIT; ++k) {
    __syncthreads();
    char* A = (k & 1) ? A1 : A0;
    char* B = (k & 1) ? B1 : B0;
    float4 t0[4], t1[4];
    const bool pf = (k + 1 < NIT);
    if (pf) {
      char* Bn = (k & 1) ? B0 : B1;
      const int koff = (k + 1) << 6;
#pragma unroll
      for (int c = 0; c < 4; ++c) {
        t0[c] = *(const float4*)(aS[c] + koff);
        t1[c] = *(const float4*)(aS[c] + koff + 4);
        async_load16(bP[c] + koff, Bn + (wave * 32 + c * 8) * 128);
      }
    }
#pragma unroll
    for (int ks = 0; ks < 2; ++ks) {
      const int u = ((((ks << 2) + quad) ^ (sw & 7)) << 4);
      bf16x8 aF[4], bF[4];
#pragma unroll
      for (int i = 0; i < 4; ++i) {
        aF[i] = *(const bf16x8*)(A + (mA + i * 16) * 128 + u);
        bF[i] = *(const bf16x8*)(B + (nB + i * 16) * 128 + u);
      }
#pragma unroll
      for (int i = 0; i < 4; ++i)
#pragma unroll
        for (int j = 0; j < 4; ++j)
          acc[i][j] = __builtin_amdgcn_mfma_f32_16x16x32_bf16(aF[i], bF[j], acc[i][j], 0, 0, 0);
    }
    if (pf) {
      char* An = (k & 1) ? A0 : A1;
#pragma unroll
      for (int c = 0; c < 4; ++c) {
        uint4 pk;
        pk.x = cvt_pk_bf16(t0[c].x, t0[c].y);
        pk.y = cvt_pk_bf16(t0[c].z, t0[c].w);
        pk.z = cvt_pk_bf16(t1[c].x, t1[c].y);
        pk.w = cvt_pk_bf16(t1[c].z, t1[c].w);
        *(uint4*)(An + ldsA[c]) = pk;
      }
    }
  }
  const float* bg = b1 + g * H1;
  float bj[4];
#pragma unroll
  for (int j = 0; j < 4; ++j) bj[j] = bg[col0 + wn * 64 + j * 16 + sw];
  const int vrows = min(128, seg1 - row0);
  epilogue_bf16(smem, acc, bj, tid, h1out, H1, row0, col0, vrows);
}

// ------------- GEMM2 tile, dbuf 128x128 (best-measured form) -------------
__device__ void gemm2_tile(const unsigned short* __restrict__ h1in,
                           const unsigned short* __restrict__ W2T,
                           const float* __restrict__ b2,
                           unsigned short* __restrict__ hfout,
                           int T, char* smem, int tid) {
  const int row0 = (T & 63) * 128, col0 = (T >> 6) * 128;
  const int lane = tid & 63, wave = tid >> 6;
  const int wm = wave & 1, wn = wave >> 1;
  const int sw = lane & 15, quad = lane >> 4;
  const int gcol = ((lane & 7) ^ (lane >> 3)) << 3;
  const unsigned short* aP[4];
  const unsigned short* bP[4];
#pragma unroll
  for (int c = 0; c < 4; ++c) {
    const int rl = wave * 32 + c * 8 + (lane >> 3);
    aP[c] = h1in + (size_t)(row0 + rl) * H1 + gcol;
    bP[c] = W2T + (size_t)(col0 + rl) * H1 + gcol;
  }
  char* A0 = smem;          char* A1 = smem + 16384;
  char* B0 = smem + 32768;  char* B1 = smem + 49152;
  const int mA = wm * 64 + sw, nB = wn * 64 + sw;
  f32x4 acc[4][4] = {};
#pragma unroll
  for (int c = 0; c < 4; ++c) {
    async_load16(aP[c], A0 + (wave * 32 + c * 8) * 128);
    async_load16(bP[c], B0 + (wave * 32 + c * 8) * 128);
  }
  const int NIT = H1 >> 6;
#pragma unroll 2
  for (int k = 0; k < NIT; ++k) {
    __syncthreads();
    char* A = (k & 1) ? A1 : A0;
    char* B = (k & 1) ? B1 : B0;
    if (k + 1 < NIT) {
      char* An = (k & 1) ? A0 : A1;
      char* Bn = (k & 1) ? B0 : B1;
      const int koff = (k + 1) << 6;
#pragma unroll
      for (int c = 0; c < 4; ++c) {
        async_load16(aP[c] + koff, An + (wave * 32 + c * 8) * 128);
        async_load16(bP[c] + koff, Bn + (wave * 32 + c * 8) * 128);
      }
    }
#pragma unroll
    for (int ks = 0; ks < 2; ++ks) {
      const int u = ((((ks << 2) + quad) ^ (sw & 7)) << 4);
      bf16x8 aF[4], bF[4];
#pragma unroll
      for (int i = 0; i < 4; ++i) {
        aF[i] = *(const bf16x8*)(A + (mA + i * 16) * 128 + u);
        bF[i] = *(const bf16x8*)(B + (nB + i * 16) * 128 + u);
      }
#pragma unroll
      for (int i = 0; i < 4; ++i)
#pragma unroll
        for (int j = 0; j < 4; ++j)
          acc[i][j] = __builtin_amdgcn_mfma_f32_16x16x32_bf16(aF[i], bF[j], acc[i][j], 0, 0, 0);
    }
  }
  float bj[4];
#pragma unroll
  for (int j = 0; j < 4; ++j) bj[j] = b2[col0 + wn * 64 + j * 16 + sw];
  epilogue_bf16(smem, acc, bj, tid, hfout, H2, row0, col0, 128);
}

// ------------- GEMM3 tile: 16x128, dbuf BK=64 — ~520 blocks = 2/CU -------------
__device__ void gemm3_tile(const unsigned short* __restrict__ hf,
                           const unsigned short* __restrict__ W3T,
                           const float* __restrict__ b3,
                           const int* __restrict__ off,
                           const int* __restrict__ perm,
                           float* __restrict__ outp,
                           int T, char* smem, int tid) {
  int g, seg1, row0;
  if (!seg_map16(off, T, g, seg1, row0)) return;
  const int lane = tid & 63, wave = tid >> 6;
  const int sw = lane & 15, quad = lane >> 4;
  const int gcol = ((lane & 7) ^ (lane >> 3)) << 3;
  int q0 = row0 + (wave & 1) * 8 + (lane >> 3);
  if (q0 > seg1 - 1) q0 = seg1 - 1;
  const unsigned short* aP = hf + (size_t)perm[q0] * H2 + gcol;
  const unsigned short* bP[4];
#pragma unroll
  for (int c = 0; c < 4; ++c) {
    const int rl = wave * 32 + c * 8 + (lane >> 3);
    bP[c] = W3T + (size_t)g * A_DIM * H2 + (size_t)rl * H2 + gcol;
  }
  char* A0 = smem;         char* A1 = smem + 4096;
  char* B0 = smem + 8192;  char* B1 = smem + 24576;
  const int nB = wave * 32 + sw;
  f32x4 acc[2] = {};
  if (wave < 2) async_load16(aP, A0 + (wave * 8) * 128);
#pragma unroll
  for (int c = 0; c < 4; ++c)
    async_load16(bP[c], B0 + (wave * 32 + c * 8) * 128);
#pragma unroll 2
  for (int k = 0; k < (H2 >> 6); ++k) {
    __syncthreads();
    char* A = (k & 1) ? A1 : A0;
    char* B = (k & 1) ? B1 : B0;
    if (k + 1 < (H2 >> 6)) {
      char* An = (k & 1) ? A0 : A1;
      char* Bn = (k & 1) ? B0 : B1;
      const int koff = (k + 1) << 6;
      if (wave < 2) async_load16(aP + koff, An + (wave * 8) * 128);
#pragma unroll
      for (int c = 0; c < 4; ++c)
        async_load16(bP[c] + koff, Bn + (wave * 32 + c * 8) * 128);
    }
#pragma unroll
    for (int ks = 0; ks < 2; ++ks) {
      const int u = ((((ks << 2) + quad) ^ (sw & 7)) << 4);
      const bf16x8 aF = *(const bf16x8*)(A + sw * 128 + u);
      bf16x8 bF[2];
#pragma unroll
      for (int j = 0; j < 2; ++j)
        bF[j] = *(const bf16x8*)(B + (nB + j * 16) * 128 + u);
#pragma unroll
      for (int j = 0; j < 2; ++j)
        acc[j] = __builtin_amdgcn_mfma_f32_16x16x32_bf16(aF, bF[j], acc[j], 0, 0, 0);
    }
  }
  const float* bg = b3 + g * A_DIM;
  float bj[2];
#pragma unroll
  for (int j = 0; j < 2; ++j) bj[j] = bg[wave * 32 + j * 16 + sw];
  __syncthreads();
#pragma unroll
  for (int j = 0; j < 2; ++j)
#pragma unroll
    for (int r = 0; r < 4; ++r) {
      const int row = quad * 4 + r;
      const int col = wave * 32 + j * 16 + sw;
      *(float*)(smem + row * 528 + col * 4) = tanhf(acc[j][r] + bj[j]);
    }
  __syncthreads();
#pragma unroll
  for (int qq = 0; qq < 2; ++qq) {
    const int idxq = qq * 256 + tid;
    const int row = idxq >> 5, ch = idxq & 31;
    if (row0 + row < seg1) {
      const uint4 v = *(const uint4*)(smem + row * 528 + ch * 16);
      *(uint4*)((char*)outp + ((size_t)perm[row0 + row] * A_DIM + ch * 4) * 4) = v;
    }
  }
}

// ================= 5-kernel pipeline =========
// k_pre: 32 histogram blocks (parallel sort phase A) + 1024 W1T tiles.
__global__ __launch_bounds__(256) void k_pre(const float* __restrict__ W1,
                                             const int* __restrict__ idx,
                                             unsigned short* __restrict__ W1T,
                                             int* __restrict__ cnt) {
  __shared__ __align__(16) char tsmem[8704];
  const int b = blockIdx.x;
  if (b < 32) {
    hist_chunk(idx, cnt, b);
  } else {
    const int r0 = b - 32, z = r0 >> 7, r = r0 & 127;
    trans_tile_ws(tsmem, W1, W1T, D_IN, H1, r & 15, r >> 4, z);
  }
}

// k_sort: 32 scatter blocks (sort phase B+C) + W2T (256) + W3T (256).
__global__ __launch_bounds__(256) void k_sort(const int* __restrict__ idx,
                                              const int* __restrict__ cnt,
                                              const float* __restrict__ W2,
                                              const float* __restrict__ W3,
                                              int* __restrict__ perm,
                                              int* __restrict__ off,
                                              unsigned short* __restrict__ W2T,
                                              unsigned short* __restrict__ W3T) {
  __shared__ __align__(16) char tsmem[8704];
  const int b = blockIdx.x;
  if (b < 32) {
    scatter_chunk(idx, cnt, perm, off, b);
  } else if (b < 288) {
    const int t = b - 32;
    trans_tile_ws(tsmem, W2, W2T, H1, H2, t & 15, t >> 4, 0);
  } else {
    const int t = b - 288, r = t & 31, z = t >> 5;
    trans_tile_ws(tsmem, W3, W3T, H2, A_DIM, r & 1, r >> 1, z);
  }
}

// k_g1: pure gemm1, 576 blocks.
__global__ __launch_bounds__(256, 2) void k_g1(const float* __restrict__ state,
                                               const int* __restrict__ perm,
                                               const unsigned short* __restrict__ W1T,
                                               const float* __restrict__ b1,
                                               const int* __restrict__ off,
                                               unsigned short* __restrict__ h1out) {
  __shared__ __align__(16) char smem[65536];
  gemm1_tile(state, perm, W1T, b1, off, h1out, blockIdx.x, smem, threadIdx.x);
}

__global__ __launch_bounds__(256) void k_g2(const unsigned short* __restrict__ h1in,
                                            const unsigned short* __restrict__ W2T,
                                            const float* __restrict__ b2,
                                            unsigned short* __restrict__ hfout) {
  __shared__ __align__(16) char smem[65536];
  gemm2_tile(h1in, W2T, b2, hfout, blockIdx.x, smem, threadIdx.x);
}

__global__ __launch_bounds__(256) void k_g3(const unsigned short* __restrict__ hf,
                                            const unsigned short* __restrict__ W3T,
                                            const float* __restrict__ b3,
                                            const int* __restrict__ off,
                                            const int* __restrict__ perm,
                                            float* __restrict__ outp) {
  __shared__ __align__(16) char smem[40960];
  gemm3_tile(hf, W3T, b3, off, perm, outp, blockIdx.x, smem, threadIdx.x);
}

extern "C" void kernel_launch(void* const* d_in, const int* in_sizes, int n_in,
                              void* d_out, int out_size, void* d_ws, size_t ws_size,
                              hipStream_t stream) {
  (void)in_sizes; (void)n_in; (void)out_size; (void)ws_size;
  const float* state = (const float*)d_in[0];
  const int*   idx   = (const int*)d_in[1];
  const float* W1    = (const float*)d_in[2];
  const float* b1    = (const float*)d_in[3];
  const float* W2    = (const float*)d_in[4];
  const float* b2    = (const float*)d_in[5];
  const float* W3    = (const float*)d_in[6];
  const float* b3    = (const float*)d_in[7];
  float* outp = (float*)d_out;
  char* ws = (char*)d_ws;
  int* off  = (int*)(ws + WS_OFF);
  int* perm = (int*)(ws + WS_PERM);
  int* cnt  = (int*)(ws + WS_CNT);
  unsigned short* W1T   = (unsigned short*)(ws + WS_W1T);
  unsigned short* W2T   = (unsigned short*)(ws + WS_W2T);
  unsigned short* W3T   = (unsigned short*)(ws + WS_W3T);
  unsigned short* h1    = (unsigned short*)(ws + WS_H1);
  unsigned short* hf    = (unsigned short*)(ws + WS_HF);

  hipLaunchKernelGGL(k_pre, dim3(1056), dim3(256), 0, stream, W1, idx, W1T, cnt);
  hipLaunchKernelGGL(k_sort, dim3(544), dim3(256), 0, stream,
                     idx, cnt, W2, W3, perm, off, W2T, W3T);
  hipLaunchKernelGGL(k_g1, dim3(576), dim3(256), 0, stream,
                     state, perm, W1T, b1, off, h1);
  hipLaunchKernelGGL(k_g2, dim3(512), dim3(256), 0, stream, h1, W2T, b2, hf);
  hipLaunchKernelGGL(k_g3, dim3(520), dim3(256), 0, stream, hf, W3T, b3, off, perm, outp);
}

// Round 11
// 148.932 us; speedup vs baseline: 1.0559x; 1.0251x over previous
//
#include <hip/hip_runtime.h>
#include <math.h>

#define G_GAMES 8
#define D_IN 512
#define H1 1024
#define H2 1024
#define A_DIM 128
#define B_ROWS 8192

typedef short bf16x8 __attribute__((ext_vector_type(8)));
typedef float f32x4 __attribute__((ext_vector_type(4)));

// ---------- workspace layout (bytes) ----------
#define WS_OFF   0u
#define WS_PERM  256u
#define WS_SPERM 33280u
#define WS_W1T   (WS_SPERM + B_ROWS*D_IN*2u)          // G*H1*D_IN bf16
#define WS_W2T   (WS_W1T + G_GAMES*D_IN*H1*2u)        // H2*H1 bf16
#define WS_W3T   (WS_W2T + (unsigned)H1*H2*2u)        // G*A*H2 bf16
#define WS_H1    (WS_W3T + G_GAMES*H2*A_DIM*2u)       // B*H1 bf16
#define WS_HF    WS_SPERM

__device__ __forceinline__ unsigned short f2bf(float x) {
  union { float f; unsigned int u; } v; v.f = x;
  unsigned int r = v.u + 0x7fffu + ((v.u >> 16) & 1u);
  return (unsigned short)(r >> 16);
}

__device__ __forceinline__ unsigned int cvt_pk_bf16(float lo, float hi) {
  unsigned int r;
  asm("v_cvt_pk_bf16_f32 %0, %1, %2" : "=v"(r) : "v"(lo), "v"(hi));
  return r;
}

__device__ __forceinline__ void async_load16(const void* gptr, void* ldsptr) {
  __builtin_amdgcn_global_load_lds(
      (const __attribute__((address_space(1))) unsigned int*)gptr,
      (__attribute__((address_space(3))) unsigned int*)ldsptr,
      16, 0, 0);
}

// ---------------- parallel stable counting sort, single-kernel form ----------------
// Each of the 32 sort blocks recomputes the FULL 32x8 histogram locally (idx is
// 32 KB, L2-resident; wave w histograms chunks [w*8, w*8+8) via ballots), then
// scatters its own chunk. dest = gameOff[g] + chunkPrefix[chunk][g] + waveOff +
// rankInWave; (chunk,wave,lane) = original order -> stable. One store/thread.
__device__ void sort_chunk_full(const int* __restrict__ idx,
                                int* __restrict__ perm, int* __restrict__ off,
                                int chunk) {
  __shared__ int scnt[32][8];
  __shared__ int cbase[8];
  __shared__ int wcn[4][8];
  const int t = threadIdx.x, lane = t & 63, wave = t >> 6;
  // full histogram: wave w computes chunks w*8 .. w*8+7 (alone -> no cross-wave sum)
#pragma unroll
  for (int i = 0; i < 8; ++i) {
    const int cc = wave * 8 + i;
    int tot[8] = {0,0,0,0,0,0,0,0};
#pragma unroll
    for (int sub = 0; sub < 4; ++sub) {
      const int g = idx[cc * 256 + sub * 64 + lane];
#pragma unroll
      for (int g0 = 0; g0 < 8; ++g0) {
        const unsigned long long m = __ballot(g == g0);
        tot[g0] += __popcll(m);          // same value in all lanes
      }
    }
    if (lane == 0) {
#pragma unroll
      for (int g0 = 0; g0 < 8; ++g0) scnt[cc][g0] = tot[g0];  // static idx
    }
  }
  __syncthreads();
  // per-game global offsets + this chunk's prefix (threads 0..7)
  if (t < 8) {
    int gt[8];
#pragma unroll
    for (int gg = 0; gg < 8; ++gg) {
      int s = 0;
      for (int c = 0; c < 32; ++c) s += scnt[c][gg];
      gt[gg] = s;
    }
    int go = 0;
#pragma unroll
    for (int gg = 0; gg < 8; ++gg) if (gg < t) go += gt[gg];
    int cp = 0;
    for (int c = 0; c < chunk; ++c) cp += scnt[c][t];
    cbase[t] = go + cp;
    if (chunk == 0) {
      off[t] = go;
      if (t == 7) off[8] = go + gt[7];
    }
  }
  // per-wave ballot rank for own chunk
  const int g = idx[chunk * 256 + t];
  const unsigned long long below = (1ull << lane) - 1ull;
  int rank = 0;
#pragma unroll
  for (int g0 = 0; g0 < 8; ++g0) {
    const unsigned long long m = __ballot(g == g0);
    const int r = __popcll(m & below);
    if (g0 == g) rank = r;
    if (lane == 0) wcn[wave][g0] = __popcll(m);
  }
  __syncthreads();   // cbase + wcn ready
  int wof = 0;
#pragma unroll
  for (int w = 0; w < 4; ++w)
    if (w < wave) wof += wcn[w][g];      // LDS runtime index: fine
  perm[cbase[g] + wof + rank] = chunk * 256 + t;
}

// ------------- fp32 [R][C] -> bf16 [C][R] transpose tile (64x64), LDS slice 8704B ----
__device__ void trans_tile_ws(char* ldsbuf, const float* __restrict__ in,
                              unsigned short* __restrict__ out,
                              int R, int C, int xt, int yt, int z) {
  in  += (size_t)z * R * C;
  out += (size_t)z * R * C;
  unsigned short (*tl)[68] = (unsigned short(*)[68])ldsbuf;
  const int c0 = xt * 64, r0 = yt * 64;
  const int t = threadIdx.x;
#pragma unroll
  for (int pass = 0; pass < 4; ++pass) {
    const int id = pass * 256 + t;
    const int r = id >> 4, f4c = (id & 15) << 2;
    const float4 v = *(const float4*)(in + (size_t)(r0 + r) * C + c0 + f4c);
    uint2 w;
    w.x = cvt_pk_bf16(v.x, v.y);
    w.y = cvt_pk_bf16(v.z, v.w);
    *(uint2*)&tl[r][f4c] = w;
  }
  __syncthreads();
#pragma unroll
  for (int pass = 0; pass < 2; ++pass) {
    const int cc = t >> 2, k0 = ((t & 3) << 3) + (pass << 5);
    unsigned short u[8];
#pragma unroll
    for (int j = 0; j < 8; ++j) u[j] = tl[k0 + j][cc];
    uint4 v;
    v.x = (unsigned)u[0] | ((unsigned)u[1] << 16);
    v.y = (unsigned)u[2] | ((unsigned)u[3] << 16);
    v.z = (unsigned)u[4] | ((unsigned)u[5] << 16);
    v.w = (unsigned)u[6] | ((unsigned)u[7] << 16);
    *(uint4*)(out + (size_t)(c0 + cc) * R + r0 + k0) = v;
  }
}

__device__ __forceinline__ bool seg_map(const int* __restrict__ off, int T,
                                        int& g, int& seg1, int& row0) {
  int base = 0;
  for (int gg = 0; gg < 8; ++gg) {
    const int s = off[gg], e = off[gg + 1];
    const int nt = (e - s + 127) >> 7;
    if (T < base + nt) { g = gg; seg1 = e; row0 = s + (T - base) * 128; return true; }
    base += nt;
  }
  return false;
}

__device__ __forceinline__ bool seg_map16(const int* __restrict__ off, int T,
                                          int& g, int& seg1, int& row0) {
  int base = 0;
  for (int gg = 0; gg < 8; ++gg) {
    const int s = off[gg], e = off[gg + 1];
    const int nt = (e - s + 15) >> 4;
    if (T < base + nt) { g = gg; seg1 = e; row0 = s + (T - base) * 16; return true; }
    base += nt;
  }
  return false;
}

// Epilogue: stage bf16 C-tile in LDS (row stride 264 B), then 16B/lane row stores.
__device__ __forceinline__ void epilogue_bf16(char* smem, const f32x4 acc[4][4],
                                              const float* bj, int tid,
                                              unsigned short* __restrict__ outp,
                                              size_t ldOut, int row0, int col0,
                                              int vrows) {
  const int lane = tid & 63, wave = tid >> 6;
  const int wm = wave & 1, wn = wave >> 1;
  const int sw = lane & 15, quad = lane >> 4;
  __syncthreads();
#pragma unroll
  for (int i = 0; i < 4; ++i)
#pragma unroll
    for (int j = 0; j < 4; ++j)
#pragma unroll
      for (int r = 0; r < 4; ++r) {
        const int row = wm * 64 + i * 16 + quad * 4 + r;
        const int col = wn * 64 + j * 16 + sw;
        const float v = fmaxf(acc[i][j][r] + bj[j], 0.0f);
        *(unsigned short*)(smem + row * 264 + col * 2) = f2bf(v);
      }
  __syncthreads();
#pragma unroll
  for (int q = 0; q < 8; ++q) {
    const int idxq = q * 256 + tid;
    const int row = idxq >> 4, ch = idxq & 15;
    if (row < vrows) {
      const uint2 lo = *(const uint2*)(smem + row * 264 + ch * 16);
      const uint2 hi = *(const uint2*)(smem + row * 264 + ch * 16 + 8);
      uint4 v; v.x = lo.x; v.y = lo.y; v.z = hi.x; v.w = hi.y;
      *(uint4*)((char*)outp + ((size_t)(row0 + row) * ldOut + col0 + ch * 8) * 2) = v;
    }
  }
}

// ------------- GEMM1 tile (fused gather), dbuf, 128x128 (best-measured) ----
__device__ void gemm1_tile(const float* __restrict__ state,
                           const int* __restrict__ perm,
                           const unsigned short* __restrict__ W1T,
                           const float* __restrict__ b1,
                           const int* __restrict__ off,
                           unsigned short* __restrict__ h1out,
                           int T, char* smem, int tid) {
  int g, seg1, row0;
  if (!seg_map(off, T % 72, g, seg1, row0)) return;
  const int col0 = (T / 72) * 128;
  const int lane = tid & 63, wave = tid >> 6;
  const int wm = wave & 1, wn = wave >> 1;
  const int sw = lane & 15, quad = lane >> 4;
  const int lc = lane & 7;
  const int gcol = ((lane & 7) ^ (lane >> 3)) << 3;
  const float* aS[4];
  int ldsA[4];
  const unsigned short* bP[4];
#pragma unroll
  for (int c = 0; c < 4; ++c) {
    const int rl = wave * 32 + c * 8 + (lane >> 3);
    int p = row0 + rl;
    if (p > seg1 - 1) p = seg1 - 1;
    aS[c]  = state + (size_t)perm[p] * D_IN + lc * 8;
    ldsA[c] = rl * 128 + ((lc ^ (rl & 7)) << 4);
    bP[c]  = W1T + (size_t)g * H1 * D_IN + (size_t)(col0 + rl) * D_IN + gcol;
  }
  char* A0 = smem;          char* A1 = smem + 16384;
  char* B0 = smem + 32768;  char* B1 = smem + 49152;
  const int mA = wm * 64 + sw, nB = wn * 64 + sw;
  f32x4 acc[4][4] = {};
  {
    float4 t0[4], t1[4];
#pragma unroll
    for (int c = 0; c < 4; ++c) {
      t0[c] = *(const float4*)(aS[c]);
      t1[c] = *(const float4*)(aS[c] + 4);
      async_load16(bP[c], B0 + (wave * 32 + c * 8) * 128);
    }
#pragma unroll
    for (int c = 0; c < 4; ++c) {
      uint4 pk;
      pk.x = cvt_pk_bf16(t0[c].x, t0[c].y);
      pk.y = cvt_pk_bf16(t0[c].z, t0[c].w);
      pk.z = cvt_pk_bf16(t1[c].x, t1[c].y);
      pk.w = cvt_pk_bf16(t1[c].z, t1[c].w);
      *(uint4*)(A0 + ldsA[c]) = pk;
    }
  }
  const int NIT = D_IN >> 6;
#pragma unroll 2
  for (int k = 0; k < NIT; ++k) {
    __syncthreads();
    char* A = (k & 1) ? A1 : A0;
    char* B = (k & 1) ? B1 : B0;
    float4 t0[4], t1[4];
    const bool pf = (k + 1 < NIT);
    if (pf) {
      char* Bn = (k & 1) ? B0 : B1;
      const int koff = (k + 1) << 6;
#pragma unroll
      for (int c = 0; c < 4; ++c) {
        t0[c] = *(const float4*)(aS[c] + koff);
        t1[c] = *(const float4*)(aS[c] + koff + 4);
        async_load16(bP[c] + koff, Bn + (wave * 32 + c * 8) * 128);
      }
    }
#pragma unroll
    for (int ks = 0; ks < 2; ++ks) {
      const int u = ((((ks << 2) + quad) ^ (sw & 7)) << 4);
      bf16x8 aF[4], bF[4];
#pragma unroll
      for (int i = 0; i < 4; ++i) {
        aF[i] = *(const bf16x8*)(A + (mA + i * 16) * 128 + u);
        bF[i] = *(const bf16x8*)(B + (nB + i * 16) * 128 + u);
      }
#pragma unroll
      for (int i = 0; i < 4; ++i)
#pragma unroll
        for (int j = 0; j < 4; ++j)
          acc[i][j] = __builtin_amdgcn_mfma_f32_16x16x32_bf16(aF[i], bF[j], acc[i][j], 0, 0, 0);
    }
    if (pf) {
      char* An = (k & 1) ? A0 : A1;
#pragma unroll
      for (int c = 0; c < 4; ++c) {
        uint4 pk;
        pk.x = cvt_pk_bf16(t0[c].x, t0[c].y);
        pk.y = cvt_pk_bf16(t0[c].z, t0[c].w);
        pk.z = cvt_pk_bf16(t1[c].x, t1[c].y);
        pk.w = cvt_pk_bf16(t1[c].z, t1[c].w);
        *(uint4*)(An + ldsA[c]) = pk;
      }
    }
  }
  const float* bg = b1 + g * H1;
  float bj[4];
#pragma unroll
  for (int j = 0; j < 4; ++j) bj[j] = bg[col0 + wn * 64 + j * 16 + sw];
  const int vrows = min(128, seg1 - row0);
  epilogue_bf16(smem, acc, bj, tid, h1out, H1, row0, col0, vrows);
}

// ------------- GEMM2 tile, dbuf 128x128 (best-measured form) -------------
__device__ void gemm2_tile(const unsigned short* __restrict__ h1in,
                           const unsigned short* __restrict__ W2T,
                           const float* __restrict__ b2,
                           unsigned short* __restrict__ hfout,
                           int T, char* smem, int tid) {
  const int row0 = (T & 63) * 128, col0 = (T >> 6) * 128;
  const int lane = tid & 63, wave = tid >> 6;
  const int wm = wave & 1, wn = wave >> 1;
  const int sw = lane & 15, quad = lane >> 4;
  const int gcol = ((lane & 7) ^ (lane >> 3)) << 3;
  const unsigned short* aP[4];
  const unsigned short* bP[4];
#pragma unroll
  for (int c = 0; c < 4; ++c) {
    const int rl = wave * 32 + c * 8 + (lane >> 3);
    aP[c] = h1in + (size_t)(row0 + rl) * H1 + gcol;
    bP[c] = W2T + (size_t)(col0 + rl) * H1 + gcol;
  }
  char* A0 = smem;          char* A1 = smem + 16384;
  char* B0 = smem + 32768;  char* B1 = smem + 49152;
  const int mA = wm * 64 + sw, nB = wn * 64 + sw;
  f32x4 acc[4][4] = {};
#pragma unroll
  for (int c = 0; c < 4; ++c) {
    async_load16(aP[c], A0 + (wave * 32 + c * 8) * 128);
    async_load16(bP[c], B0 + (wave * 32 + c * 8) * 128);
  }
  const int NIT = H1 >> 6;
#pragma unroll 2
  for (int k = 0; k < NIT; ++k) {
    __syncthreads();
    char* A = (k & 1) ? A1 : A0;
    char* B = (k & 1) ? B1 : B0;
    if (k + 1 < NIT) {
      char* An = (k & 1) ? A0 : A1;
      char* Bn = (k & 1) ? B0 : B1;
      const int koff = (k + 1) << 6;
#pragma unroll
      for (int c = 0; c < 4; ++c) {
        async_load16(aP[c] + koff, An + (wave * 32 + c * 8) * 128);
        async_load16(bP[c] + koff, Bn + (wave * 32 + c * 8) * 128);
      }
    }
#pragma unroll
    for (int ks = 0; ks < 2; ++ks) {
      const int u = ((((ks << 2) + quad) ^ (sw & 7)) << 4);
      bf16x8 aF[4], bF[4];
#pragma unroll
      for (int i = 0; i < 4; ++i) {
        aF[i] = *(const bf16x8*)(A + (mA + i * 16) * 128 + u);
        bF[i] = *(const bf16x8*)(B + (nB + i * 16) * 128 + u);
      }
#pragma unroll
      for (int i = 0; i < 4; ++i)
#pragma unroll
        for (int j = 0; j < 4; ++j)
          acc[i][j] = __builtin_amdgcn_mfma_f32_16x16x32_bf16(aF[i], bF[j], acc[i][j], 0, 0, 0);
    }
  }
  float bj[4];
#pragma unroll
  for (int j = 0; j < 4; ++j) bj[j] = b2[col0 + wn * 64 + j * 16 + sw];
  epilogue_bf16(smem, acc, bj, tid, hfout, H2, row0, col0, 128);
}

// ------------- GEMM3 tile: 16x128, dbuf BK=64 — ~520 blocks = 2/CU -------------
__device__ void gemm3_tile(const unsigned short* __restrict__ hf,
                           const unsigned short* __restrict__ W3T,
                           const float* __restrict__ b3,
                           const int* __restrict__ off,
                           const int* __restrict__ perm,
                           float* __restrict__ outp,
                           int T, char* smem, int tid) {
  int g, seg1, row0;
  if (!seg_map16(off, T, g, seg1, row0)) return;
  const int lane = tid & 63, wave = tid >> 6;
  const int sw = lane & 15, quad = lane >> 4;
  const int gcol = ((lane & 7) ^ (lane >> 3)) << 3;
  int q0 = row0 + (wave & 1) * 8 + (lane >> 3);
  if (q0 > seg1 - 1) q0 = seg1 - 1;
  const unsigned short* aP = hf + (size_t)perm[q0] * H2 + gcol;
  const unsigned short* bP[4];
#pragma unroll
  for (int c = 0; c < 4; ++c) {
    const int rl = wave * 32 + c * 8 + (lane >> 3);
    bP[c] = W3T + (size_t)g * A_DIM * H2 + (size_t)rl * H2 + gcol;
  }
  char* A0 = smem;         char* A1 = smem + 4096;
  char* B0 = smem + 8192;  char* B1 = smem + 24576;
  const int nB = wave * 32 + sw;
  f32x4 acc[2] = {};
  if (wave < 2) async_load16(aP, A0 + (wave * 8) * 128);
#pragma unroll
  for (int c = 0; c < 4; ++c)
    async_load16(bP[c], B0 + (wave * 32 + c * 8) * 128);
#pragma unroll 2
  for (int k = 0; k < (H2 >> 6); ++k) {
    __syncthreads();
    char* A = (k & 1) ? A1 : A0;
    char* B = (k & 1) ? B1 : B0;
    if (k + 1 < (H2 >> 6)) {
      char* An = (k & 1) ? A0 : A1;
      char* Bn = (k & 1) ? B0 : B1;
      const int koff = (k + 1) << 6;
      if (wave < 2) async_load16(aP + koff, An + (wave * 8) * 128);
#pragma unroll
      for (int c = 0; c < 4; ++c)
        async_load16(bP[c] + koff, Bn + (wave * 32 + c * 8) * 128);
    }
#pragma unroll
    for (int ks = 0; ks < 2; ++ks) {
      const int u = ((((ks << 2) + quad) ^ (sw & 7)) << 4);
      const bf16x8 aF = *(const bf16x8*)(A + sw * 128 + u);
      bf16x8 bF[2];
#pragma unroll
      for (int j = 0; j < 2; ++j)
        bF[j] = *(const bf16x8*)(B + (nB + j * 16) * 128 + u);
#pragma unroll
      for (int j = 0; j < 2; ++j)
        acc[j] = __builtin_amdgcn_mfma_f32_16x16x32_bf16(aF, bF[j], acc[j], 0, 0, 0);
    }
  }
  const float* bg = b3 + g * A_DIM;
  float bj[2];
#pragma unroll
  for (int j = 0; j < 2; ++j) bj[j] = bg[wave * 32 + j * 16 + sw];
  __syncthreads();
#pragma unroll
  for (int j = 0; j < 2; ++j)
#pragma unroll
    for (int r = 0; r < 4; ++r) {
      const int row = quad * 4 + r;
      const int col = wave * 32 + j * 16 + sw;
      *(float*)(smem + row * 528 + col * 4) = tanhf(acc[j][r] + bj[j]);
    }
  __syncthreads();
#pragma unroll
  for (int qq = 0; qq < 2; ++qq) {
    const int idxq = qq * 256 + tid;
    const int row = idxq >> 5, ch = idxq & 31;
    if (row0 + row < seg1) {
      const uint4 v = *(const uint4*)(smem + row * 528 + ch * 16);
      *(uint4*)((char*)outp + ((size_t)perm[row0 + row] * A_DIM + ch * 4) * 4) = v;
    }
  }
}

// ================= 4-kernel pipeline =========
// k_pre: 32 self-sufficient sort blocks + ALL 1536 transpose tiles.
__global__ __launch_bounds__(256) void k_pre(const float* __restrict__ W1,
                                             const float* __restrict__ W2,
                                             const float* __restrict__ W3,
                                             const int* __restrict__ idx,
                                             unsigned short* __restrict__ W1T,
                                             unsigned short* __restrict__ W2T,
                                             unsigned short* __restrict__ W3T,
                                             int* __restrict__ perm,
                                             int* __restrict__ off) {
  __shared__ __align__(16) char tsmem[8704];
  const int b = blockIdx.x;
  if (b < 32) {
    sort_chunk_full(idx, perm, off, b);
    return;
  }
  const int r0 = b - 32;
  if (r0 < 1024) {
    const int z = r0 >> 7, r = r0 & 127;
    trans_tile_ws(tsmem, W1, W1T, D_IN, H1, r & 15, r >> 4, z);
  } else if (r0 < 1280) {
    const int t = r0 - 1024;
    trans_tile_ws(tsmem, W2, W2T, H1, H2, t & 15, t >> 4, 0);
  } else {
    const int t = r0 - 1280, r = t & 31, z = t >> 5;
    trans_tile_ws(tsmem, W3, W3T, H2, A_DIM, r & 1, r >> 1, z);
  }
}

// k_g1: pure gemm1, 576 blocks.
__global__ __launch_bounds__(256, 2) void k_g1(const float* __restrict__ state,
                                               const int* __restrict__ perm,
                                               const unsigned short* __restrict__ W1T,
                                               const float* __restrict__ b1,
                                               const int* __restrict__ off,
                                               unsigned short* __restrict__ h1out) {
  __shared__ __align__(16) char smem[65536];
  gemm1_tile(state, perm, W1T, b1, off, h1out, blockIdx.x, smem, threadIdx.x);
}

__global__ __launch_bounds__(256) void k_g2(const unsigned short* __restrict__ h1in,
                                            const unsigned short* __restrict__ W2T,
                                            const float* __restrict__ b2,
                                            unsigned short* __restrict__ hfout) {
  __shared__ __align__(16) char smem[65536];
  gemm2_tile(h1in, W2T, b2, hfout, blockIdx.x, smem, threadIdx.x);
}

__global__ __launch_bounds__(256) void k_g3(const unsigned short* __restrict__ hf,
                                            const unsigned short* __restrict__ W3T,
                                            const float* __restrict__ b3,
                                            const int* __restrict__ off,
                                            const int* __restrict__ perm,
                                            float* __restrict__ outp) {
  __shared__ __align__(16) char smem[40960];
  gemm3_tile(hf, W3T, b3, off, perm, outp, blockIdx.x, smem, threadIdx.x);
}

extern "C" void kernel_launch(void* const* d_in, const int* in_sizes, int n_in,
                              void* d_out, int out_size, void* d_ws, size_t ws_size,
                              hipStream_t stream) {
  (void)in_sizes; (void)n_in; (void)out_size; (void)ws_size;
  const float* state = (const float*)d_in[0];
  const int*   idx   = (const int*)d_in[1];
  const float* W1    = (const float*)d_in[2];
  const float* b1    = (const float*)d_in[3];
  const float* W2    = (const float*)d_in[4];
  const float* b2    = (const float*)d_in[5];
  const float* W3    = (const float*)d_in[6];
  const float* b3    = (const float*)d_in[7];
  float* outp = (float*)d_out;
  char* ws = (char*)d_ws;
  int* off  = (int*)(ws + WS_OFF);
  int* perm = (int*)(ws + WS_PERM);
  unsigned short* W1T   = (unsigned short*)(ws + WS_W1T);
  unsigned short* W2T   = (unsigned short*)(ws + WS_W2T);
  unsigned short* W3T   = (unsigned short*)(ws + WS_W3T);
  unsigned short* h1    = (unsigned short*)(ws + WS_H1);
  unsigned short* hf    = (unsigned short*)(ws + WS_HF);

  hipLaunchKernelGGL(k_pre, dim3(1568), dim3(256), 0, stream,
                     W1, W2, W3, idx, W1T, W2T, W3T, perm, off);
  hipLaunchKernelGGL(k_g1, dim3(576), dim3(256), 0, stream,
                     state, perm, W1T, b1, off, h1);
  hipLaunchKernelGGL(k_g2, dim3(512), dim3(256), 0, stream, h1, W2T, b2, hf);
  hipLaunchKernelGGL(k_g3, dim3(520), dim3(256), 0, stream, hf, W3T, b3, off, perm, outp);
}